// Round 4
// baseline (2505.440 us; speedup 1.0000x reference)
//
#include <hip/hip_runtime.h>

#define NUSERS 100000
#define NITEMS 50000
#define DIM 64
#define NNZ 1600000
#define ALPHA 0.1f
#define TROWS (NUSERS + NITEMS)   // 150000 combined rows
#define LSTRIDE (TROWS * DIM)
#define NEDGES (2 * NNZ)          // 3.2M combined edges

#define BROWS 128                           // rows per bucket
#define NBUCK ((TROWS + BROWS - 1) / BROWS) // 1172
#define CH 16384                            // edges per binning block
#define NBCHUNK ((NEDGES + CH - 1) / CH)    // 196
#define YSTRIDE 65                          // LDS row stride (bank spread)

__device__ __forceinline__ unsigned short f2bf(float f) {
    unsigned u = __float_as_uint(f);
    unsigned r = (u + 0x7FFFu + ((u >> 16) & 1u)) >> 16;   // RNE
    return (unsigned short)r;
}

// ---------------- layer-0 copy (+ optional bf16 table) ----------------
template <int MAKE_BF16>
__global__ __launch_bounds__(256) void init_copy_kernel(const float4* __restrict__ ue,
                                                        const float4* __restrict__ ie,
                                                        float4* __restrict__ out,
                                                        ushort4* __restrict__ xb0) {
    const int nU4 = NUSERS * DIM / 4;
    const int nT4 = TROWS * DIM / 4;
    int i = blockIdx.x * 256 + threadIdx.x;
    if (i >= nT4) return;
    float4 v = (i < nU4) ? ue[i] : ie[i - nU4];
    out[i] = v;
    if (MAKE_BF16) {
        ushort4 b;
        b.x = f2bf(v.x); b.y = f2bf(v.y); b.z = f2bf(v.z); b.w = f2bf(v.w);
        xb0[i] = b;
    }
}

// ---------------- bucket histogram (block-privatized) ----------------
__global__ __launch_bounds__(256) void bucket_hist_kernel(const int* __restrict__ ui_rows,
                                                          const int* __restrict__ iu_rows,
                                                          int* __restrict__ gcounts) {
    __shared__ int h[NBUCK];
    for (int t = threadIdx.x; t < NBUCK; t += 256) h[t] = 0;
    __syncthreads();
    int base = blockIdx.x * CH;
    for (int j = threadIdx.x; j < CH; j += 256) {
        int i = base + j;
        if (i >= NEDGES) break;
        int crow = (i < NNZ) ? ui_rows[i] : (NUSERS + iu_rows[i - NNZ]);
        atomicAdd(&h[crow >> 7], 1);
    }
    __syncthreads();
    for (int t = threadIdx.x; t < NBUCK; t += 256) {
        int c = h[t];
        if (c) atomicAdd(&gcounts[t], c);
    }
}

// ---------------- exclusive scan of bucket counts (one wave) ----------------
__global__ void scan_buckets_kernel(const int* __restrict__ gcounts,
                                    int* __restrict__ gbase,
                                    int* __restrict__ gcursor) {
    int lane = threadIdx.x;   // blockDim = 64, single wave
    int carry = 0;
    for (int b0 = 0; b0 < NBUCK; b0 += 64) {
        int idx = b0 + lane;
        int c = (idx < NBUCK) ? gcounts[idx] : 0;
        int x = c;
        for (int off = 1; off < 64; off <<= 1) {
            int u = __shfl_up(x, off, 64);
            if (lane >= off) x += u;
        }
        int excl = carry + x - c;
        if (idx < NBUCK) { gbase[idx] = excl; gcursor[idx] = excl; }
        carry += __shfl(x, 63, 64);
    }
}

// ---------------- binned scatter: contiguous per-(block,bucket) runs ----------------
// payload word0 = src | (row_local << 18)   (src < 2^18, row_local < 128)
__global__ __launch_bounds__(256) void bin_scatter_kernel(
    const int* __restrict__ ui_rows, const int* __restrict__ ui_cols,
    const float* __restrict__ ui_vals,
    const int* __restrict__ iu_rows, const int* __restrict__ iu_cols,
    const float* __restrict__ iu_vals,
    int* __restrict__ gcursor, int2* __restrict__ binned)
{
    __shared__ int h[NBUCK];
    __shared__ int bbase[NBUCK];
    for (int t = threadIdx.x; t < NBUCK; t += 256) h[t] = 0;
    __syncthreads();
    int base = blockIdx.x * CH;
    for (int j = threadIdx.x; j < CH; j += 256) {
        int i = base + j;
        if (i >= NEDGES) break;
        int crow = (i < NNZ) ? ui_rows[i] : (NUSERS + iu_rows[i - NNZ]);
        atomicAdd(&h[crow >> 7], 1);
    }
    __syncthreads();
    for (int t = threadIdx.x; t < NBUCK; t += 256) {
        int c = h[t];
        bbase[t] = c ? atomicAdd(&gcursor[t], c) : 0;
        h[t] = 0;
    }
    __syncthreads();
    for (int j = threadIdx.x; j < CH; j += 256) {
        int i = base + j;
        if (i >= NEDGES) break;
        int crow, src; float val;
        if (i < NNZ) {
            crow = ui_rows[i]; src = NUSERS + ui_cols[i]; val = ui_vals[i];
        } else {
            int k = i - NNZ;
            crow = NUSERS + iu_rows[k]; src = iu_cols[k]; val = iu_vals[k];
        }
        int b = crow >> 7;
        int off = atomicAdd(&h[b], 1);
        binned[bbase[b] + off] = make_int2(src | ((crow & 127) << 18), __float_as_int(val));
    }
}

// ---------------- bucket pull: LDS-accumulating SpMM ----------------
// Block b owns rows [b*128, b*128+128). 32 groups x 16 lanes; each group
// processes one edge per step: lane loads 8B (bf16x4) or 16B (f32x4) of the
// source row, multiplies by val, atomically adds into LDS y.
template <int USE_BF16, int WRITE_BF16>
__global__ __launch_bounds__(512) void bucket_pull_kernel(
    const int* __restrict__ gbase, const int* __restrict__ gcounts,
    const int2* __restrict__ binned,
    const unsigned short* __restrict__ xb_prev,  // bf16 combined prev layer
    const float* __restrict__ xf_prev,           // f32 combined prev layer
    const float4* __restrict__ ue4, const float4* __restrict__ ie4,
    float4* __restrict__ outL4,                  // combined f32 output layer
    ushort4* __restrict__ xb_next)               // bf16 table for next layer
{
    __shared__ float y[BROWS * YSTRIDE];
    for (int t = threadIdx.x; t < BROWS * YSTRIDE; t += 512) y[t] = 0.f;
    __syncthreads();

    int b = blockIdx.x;
    int s = gbase[b];
    int e = s + gcounts[b];
    int g = threadIdx.x >> 4;     // group 0..31
    int sub = threadIdx.x & 15;   // 4-float slot within row

    int k = s + g;
    // 2-deep unrolled main loop: 2 independent gathers in flight per group
    for (; k + 32 < e; k += 64) {
        int2 m0 = binned[k];
        int2 m1 = binned[k + 32];
        unsigned w0 = (unsigned)m0.x, w1 = (unsigned)m1.x;
        int src0 = w0 & 0x3FFFF, src1 = w1 & 0x3FFFF;
        int rl0 = w0 >> 18, rl1 = w1 >> 18;
        float v0 = __int_as_float(m0.y), v1 = __int_as_float(m1.y);
        float a0, a1, a2, a3, b0, b1, b2, b3;
        if (USE_BF16) {
            uint2 x0 = *(const uint2*)(xb_prev + (size_t)src0 * DIM + sub * 4);
            uint2 x1 = *(const uint2*)(xb_prev + (size_t)src1 * DIM + sub * 4);
            a0 = __uint_as_float(x0.x << 16); a1 = __uint_as_float(x0.x & 0xFFFF0000u);
            a2 = __uint_as_float(x0.y << 16); a3 = __uint_as_float(x0.y & 0xFFFF0000u);
            b0 = __uint_as_float(x1.x << 16); b1 = __uint_as_float(x1.x & 0xFFFF0000u);
            b2 = __uint_as_float(x1.y << 16); b3 = __uint_as_float(x1.y & 0xFFFF0000u);
        } else {
            float4 x0 = *(const float4*)(xf_prev + (size_t)src0 * DIM + sub * 4);
            float4 x1 = *(const float4*)(xf_prev + (size_t)src1 * DIM + sub * 4);
            a0 = x0.x; a1 = x0.y; a2 = x0.z; a3 = x0.w;
            b0 = x1.x; b1 = x1.y; b2 = x1.z; b3 = x1.w;
        }
        float* y0 = &y[rl0 * YSTRIDE + sub * 4];
        float* y1 = &y[rl1 * YSTRIDE + sub * 4];
        unsafeAtomicAdd(y0 + 0, v0 * a0);
        unsafeAtomicAdd(y0 + 1, v0 * a1);
        unsafeAtomicAdd(y0 + 2, v0 * a2);
        unsafeAtomicAdd(y0 + 3, v0 * a3);
        unsafeAtomicAdd(y1 + 0, v1 * b0);
        unsafeAtomicAdd(y1 + 1, v1 * b1);
        unsafeAtomicAdd(y1 + 2, v1 * b2);
        unsafeAtomicAdd(y1 + 3, v1 * b3);
    }
    for (; k < e; k += 32) {
        int2 m0 = binned[k];
        unsigned w0 = (unsigned)m0.x;
        int src0 = w0 & 0x3FFFF;
        int rl0 = w0 >> 18;
        float v0 = __int_as_float(m0.y);
        float a0, a1, a2, a3;
        if (USE_BF16) {
            uint2 x0 = *(const uint2*)(xb_prev + (size_t)src0 * DIM + sub * 4);
            a0 = __uint_as_float(x0.x << 16); a1 = __uint_as_float(x0.x & 0xFFFF0000u);
            a2 = __uint_as_float(x0.y << 16); a3 = __uint_as_float(x0.y & 0xFFFF0000u);
        } else {
            float4 x0 = *(const float4*)(xf_prev + (size_t)src0 * DIM + sub * 4);
            a0 = x0.x; a1 = x0.y; a2 = x0.z; a3 = x0.w;
        }
        float* y0 = &y[rl0 * YSTRIDE + sub * 4];
        unsafeAtomicAdd(y0 + 0, v0 * a0);
        unsafeAtomicAdd(y0 + 1, v0 * a1);
        unsafeAtomicAdd(y0 + 2, v0 * a2);
        unsafeAtomicAdd(y0 + 3, v0 * a3);
    }
    __syncthreads();

    // epilogue: + alpha*e0, write f32 layer (and bf16 table for next layer)
    int row0 = b * BROWS;
    for (int p = threadIdx.x; p < BROWS * 16; p += 512) {
        int rl = p >> 4, c4 = p & 15;
        int crow = row0 + rl;
        if (crow >= TROWS) continue;
        const float* yr = &y[rl * YSTRIDE + c4 * 4];
        float4 e0 = (crow < NUSERS) ? ue4[(size_t)crow * 16 + c4]
                                    : ie4[(size_t)(crow - NUSERS) * 16 + c4];
        float4 a;
        a.x = fmaf(ALPHA, e0.x, yr[0]);
        a.y = fmaf(ALPHA, e0.y, yr[1]);
        a.z = fmaf(ALPHA, e0.z, yr[2]);
        a.w = fmaf(ALPHA, e0.w, yr[3]);
        outL4[(size_t)crow * 16 + c4] = a;
        if (WRITE_BF16) {
            ushort4 bb;
            bb.x = f2bf(a.x); bb.y = f2bf(a.y); bb.z = f2bf(a.z); bb.w = f2bf(a.w);
            xb_next[(size_t)crow * 16 + c4] = bb;
        }
    }
}

// ---------------- fallback (round-1 atomic path) ----------------
__global__ __launch_bounds__(256) void init_out_kernel(const float4* __restrict__ ue,
                                                       const float4* __restrict__ ie,
                                                       float4* __restrict__ out) {
    const int nU4 = NUSERS * DIM / 4;
    const int nT4 = TROWS * DIM / 4;
    int i = blockIdx.x * 256 + threadIdx.x;
    if (i >= nT4) return;
    float4 v = (i < nU4) ? ue[i] : ie[i - nU4];
    out[i] = v;
    float4 a = make_float4(ALPHA * v.x, ALPHA * v.y, ALPHA * v.z, ALPHA * v.w);
    out[nT4 + i] = a;
    out[2 * nT4 + i] = a;
}

__global__ __launch_bounds__(256) void spmm_layer_kernel(
    const int* __restrict__ ui_rows, const int* __restrict__ ui_cols,
    const float* __restrict__ ui_vals,
    const int* __restrict__ iu_rows, const int* __restrict__ iu_cols,
    const float* __restrict__ iu_vals,
    const float* __restrict__ x_items, const float* __restrict__ x_users,
    float* __restrict__ y_users, float* __restrict__ y_items)
{
    unsigned tid = blockIdx.x * 256u + threadIdx.x;
    unsigned d = tid & 63u;
    unsigned e = tid >> 6;
    if (e < NNZ) {
        int r = ui_rows[e];
        int c = ui_cols[e];
        float v = ui_vals[e];
        atomicAdd(&y_users[r * DIM + d], v * x_items[c * DIM + d]);
    } else {
        e -= NNZ;
        if (e < NNZ) {
            int r = iu_rows[e];
            int c = iu_cols[e];
            float v = iu_vals[e];
            atomicAdd(&y_items[r * DIM + d], v * x_users[c * DIM + d]);
        }
    }
}

extern "C" void kernel_launch(void* const* d_in, const int* in_sizes, int n_in,
                              void* d_out, int out_size, void* d_ws, size_t ws_size,
                              hipStream_t stream) {
    const float* ue      = (const float*)d_in[0];
    const float* ie      = (const float*)d_in[1];
    const float* ui_vals = (const float*)d_in[2];
    const float* iu_vals = (const float*)d_in[3];
    const int*   ui_rows = (const int*)d_in[4];
    const int*   ui_cols = (const int*)d_in[5];
    const int*   iu_rows = (const int*)d_in[6];
    const int*   iu_cols = (const int*)d_in[7];
    float* out = (float*)d_out;

    float* L1 = out + (size_t)LSTRIDE;
    float* L2 = out + (size_t)2 * LSTRIDE;

    // ws layout: gcounts[1280] gbase[1280] gcursor[1280] | binned int2[NEDGES]
    //            | xb0 ushort[TROWS*64] | xb1 ushort[TROWS*64]
    const size_t NB_PAD = 1280;
    const size_t hdr_bytes    = NB_PAD * 3 * 4;                      // 15360
    const size_t binned_bytes = (size_t)NEDGES * 8;                  // 25.6 MB
    const size_t xb_bytes     = (size_t)TROWS * DIM * 2;             // 19.2 MB
    const size_t need_nobf = hdr_bytes + binned_bytes;
    const size_t need_full = need_nobf + 2 * xb_bytes;

    if (ws_size < need_nobf) {
        // last-resort fallback: atomic scatter path (round-1, known-good)
        const int nT4 = TROWS * DIM / 4;
        init_out_kernel<<<(nT4 + 255) / 256, 256, 0, stream>>>(
            (const float4*)ue, (const float4*)ie, (float4*)out);
        float* u1 = L1; float* i1 = L1 + (size_t)NUSERS * DIM;
        float* u2 = L2; float* i2 = L2 + (size_t)NUSERS * DIM;
        const unsigned nblocks = (2u * NNZ * 64u) / 256u;
        spmm_layer_kernel<<<nblocks, 256, 0, stream>>>(
            ui_rows, ui_cols, ui_vals, iu_rows, iu_cols, iu_vals, ie, ue, u1, i1);
        spmm_layer_kernel<<<nblocks, 256, 0, stream>>>(
            ui_rows, ui_cols, ui_vals, iu_rows, iu_cols, iu_vals, i1, u1, u2, i2);
        return;
    }

    int* gcounts = (int*)d_ws;
    int* gbase   = gcounts + NB_PAD;
    int* gcursor = gbase + NB_PAD;
    int2* binned = (int2*)((char*)d_ws + hdr_bytes);
    unsigned short* xb0 = (unsigned short*)((char*)binned + binned_bytes);
    unsigned short* xb1 = xb0 + (size_t)TROWS * DIM;

    const bool use_bf16 = (ws_size >= need_full);

    hipMemsetAsync(gcounts, 0, NB_PAD * sizeof(int), stream);

    const int nT4 = TROWS * DIM / 4;
    if (use_bf16)
        init_copy_kernel<1><<<(nT4 + 255) / 256, 256, 0, stream>>>(
            (const float4*)ue, (const float4*)ie, (float4*)out, (ushort4*)xb0);
    else
        init_copy_kernel<0><<<(nT4 + 255) / 256, 256, 0, stream>>>(
            (const float4*)ue, (const float4*)ie, (float4*)out, nullptr);

    bucket_hist_kernel<<<NBCHUNK, 256, 0, stream>>>(ui_rows, iu_rows, gcounts);
    scan_buckets_kernel<<<1, 64, 0, stream>>>(gcounts, gbase, gcursor);
    bin_scatter_kernel<<<NBCHUNK, 256, 0, stream>>>(
        ui_rows, ui_cols, ui_vals, iu_rows, iu_cols, iu_vals, gcursor, binned);

    const float4* ue4 = (const float4*)ue;
    const float4* ie4 = (const float4*)ie;
    if (use_bf16) {
        bucket_pull_kernel<1, 1><<<NBUCK, 512, 0, stream>>>(
            gbase, gcounts, binned, xb0, nullptr, ue4, ie4, (float4*)L1, (ushort4*)xb1);
        bucket_pull_kernel<1, 0><<<NBUCK, 512, 0, stream>>>(
            gbase, gcounts, binned, xb1, nullptr, ue4, ie4, (float4*)L2, nullptr);
    } else {
        bucket_pull_kernel<0, 0><<<NBUCK, 512, 0, stream>>>(
            gbase, gcounts, binned, nullptr, out, ue4, ie4, (float4*)L1, nullptr);
        bucket_pull_kernel<0, 0><<<NBUCK, 512, 0, stream>>>(
            gbase, gcounts, binned, nullptr, L1, ue4, ie4, (float4*)L2, nullptr);
    }
}

// Round 5
// 369.065 us; speedup vs baseline: 6.7886x; 6.7886x over previous
//
#include <hip/hip_runtime.h>

#define NUSERS 100000
#define NITEMS 50000
#define DIM 64
#define NNZ 1600000
#define ALPHA 0.1f
#define TROWS (NUSERS + NITEMS)   // 150000 combined rows
#define LSTRIDE (TROWS * DIM)
#define NEDGES (2 * NNZ)          // 3.2M combined edges

#define BROWS 128                           // rows per bucket
#define NBUCK ((TROWS + BROWS - 1) / BROWS) // 1172
#define CH 16384                            // edges per binning block
#define NBCHUNK ((NEDGES + CH - 1) / CH)    // 196

__device__ __forceinline__ unsigned short f2bf(float f) {
    unsigned u = __float_as_uint(f);
    unsigned r = (u + 0x7FFFu + ((u >> 16) & 1u)) >> 16;   // RNE
    return (unsigned short)r;
}

// ---------------- layer-0 copy (+ optional bf16 table) ----------------
template <int MAKE_BF16>
__global__ __launch_bounds__(256) void init_copy_kernel(const float4* __restrict__ ue,
                                                        const float4* __restrict__ ie,
                                                        float4* __restrict__ out,
                                                        ushort4* __restrict__ xb0) {
    const int nU4 = NUSERS * DIM / 4;
    const int nT4 = TROWS * DIM / 4;
    int i = blockIdx.x * 256 + threadIdx.x;
    if (i >= nT4) return;
    float4 v = (i < nU4) ? ue[i] : ie[i - nU4];
    out[i] = v;
    if (MAKE_BF16) {
        ushort4 b;
        b.x = f2bf(v.x); b.y = f2bf(v.y); b.z = f2bf(v.z); b.w = f2bf(v.w);
        xb0[i] = b;
    }
}

// ---------------- bucket histogram (block-privatized, int LDS atomics) ----------------
__global__ __launch_bounds__(256) void bucket_hist_kernel(const int* __restrict__ ui_rows,
                                                          const int* __restrict__ iu_rows,
                                                          int* __restrict__ gcounts) {
    __shared__ int h[NBUCK];
    for (int t = threadIdx.x; t < NBUCK; t += 256) h[t] = 0;
    __syncthreads();
    int base = blockIdx.x * CH;
    for (int j = threadIdx.x; j < CH; j += 256) {
        int i = base + j;
        if (i >= NEDGES) break;
        int crow = (i < NNZ) ? ui_rows[i] : (NUSERS + iu_rows[i - NNZ]);
        atomicAdd(&h[crow >> 7], 1);
    }
    __syncthreads();
    for (int t = threadIdx.x; t < NBUCK; t += 256) {
        int c = h[t];
        if (c) atomicAdd(&gcounts[t], c);
    }
}

// ---------------- exclusive scan of bucket counts (one wave) ----------------
__global__ void scan_buckets_kernel(const int* __restrict__ gcounts,
                                    int* __restrict__ gbase,
                                    int* __restrict__ gcursor,
                                    int* __restrict__ rowptr) {
    int lane = threadIdx.x;   // blockDim = 64, single wave
    int carry = 0;
    for (int b0 = 0; b0 < NBUCK; b0 += 64) {
        int idx = b0 + lane;
        int c = (idx < NBUCK) ? gcounts[idx] : 0;
        int x = c;
        for (int off = 1; off < 64; off <<= 1) {
            int u = __shfl_up(x, off, 64);
            if (lane >= off) x += u;
        }
        int excl = carry + x - c;
        if (idx < NBUCK) { gbase[idx] = excl; gcursor[idx] = excl; }
        carry += __shfl(x, 63, 64);
    }
    if (lane == 0) rowptr[TROWS] = NEDGES;   // sentinel
}

// ---------------- binned scatter: contiguous per-(block,bucket) runs ----------------
// payload word0 = src | (row_local << 18)   (src < 2^18, row_local < 128)
__global__ __launch_bounds__(256) void bin_scatter_kernel(
    const int* __restrict__ ui_rows, const int* __restrict__ ui_cols,
    const float* __restrict__ ui_vals,
    const int* __restrict__ iu_rows, const int* __restrict__ iu_cols,
    const float* __restrict__ iu_vals,
    int* __restrict__ gcursor, int2* __restrict__ binned)
{
    __shared__ int h[NBUCK];
    __shared__ int bbase[NBUCK];
    for (int t = threadIdx.x; t < NBUCK; t += 256) h[t] = 0;
    __syncthreads();
    int base = blockIdx.x * CH;
    for (int j = threadIdx.x; j < CH; j += 256) {
        int i = base + j;
        if (i >= NEDGES) break;
        int crow = (i < NNZ) ? ui_rows[i] : (NUSERS + iu_rows[i - NNZ]);
        atomicAdd(&h[crow >> 7], 1);
    }
    __syncthreads();
    for (int t = threadIdx.x; t < NBUCK; t += 256) {
        int c = h[t];
        bbase[t] = c ? atomicAdd(&gcursor[t], c) : 0;
        h[t] = 0;
    }
    __syncthreads();
    for (int j = threadIdx.x; j < CH; j += 256) {
        int i = base + j;
        if (i >= NEDGES) break;
        int crow, src; float val;
        if (i < NNZ) {
            crow = ui_rows[i]; src = NUSERS + ui_cols[i]; val = ui_vals[i];
        } else {
            int k = i - NNZ;
            crow = NUSERS + iu_rows[k]; src = iu_cols[k]; val = iu_vals[k];
        }
        int b = crow >> 7;
        int off = atomicAdd(&h[b], 1);
        binned[bbase[b] + off] = make_int2(src | ((crow & 127) << 18), __float_as_int(val));
    }
}

// ---------------- bucket-local CSR sort: binned -> binned2 (row-sorted) ----------------
// One block per bucket. Reads/writes stay inside the bucket's ~22KB window
// (same XCD, L2-merged). Also emits the global rowptr.
__global__ __launch_bounds__(256) void csr_sort_kernel(
    const int* __restrict__ gbase, const int* __restrict__ gcounts,
    const int2* __restrict__ binned, int2* __restrict__ binned2,
    int* __restrict__ rowptr)
{
    __shared__ int h[BROWS];
    __shared__ int off[BROWS];
    __shared__ int cur[BROWS];
    int b = blockIdx.x;
    int s = gbase[b];
    int n = gcounts[b];
    int t = threadIdx.x;
    if (t < BROWS) h[t] = 0;
    __syncthreads();
    for (int j = t; j < n; j += 256)
        atomicAdd(&h[((unsigned)binned[s + j].x) >> 18], 1);
    __syncthreads();
    if (t < BROWS) off[t] = h[t];
    __syncthreads();
    for (int d = 1; d < BROWS; d <<= 1) {
        int v = 0;
        if (t < BROWS && t >= d) v = off[t - d];
        __syncthreads();
        if (t < BROWS) off[t] += v;
        __syncthreads();
    }
    if (t < BROWS) {
        int excl = off[t] - h[t];     // exclusive scan
        cur[t] = excl;
        int row = b * BROWS + t;
        if (row < TROWS) rowptr[row] = s + excl;
    }
    __syncthreads();
    for (int j = t; j < n; j += 256) {
        int2 m = binned[s + j];
        unsigned w = (unsigned)m.x;
        int pos = atomicAdd(&cur[w >> 18], 1);
        binned2[s + pos] = make_int2((int)(w & 0x3FFFFu), m.y);
    }
}

// ---------------- CSR pull: one wave per output row, register accumulate ----------------
// Wave = 4 edge-groups x 16 lanes; group covers the full feature row of its
// edge (bf16: uint2/lane = 128B; f32: float4/lane = 256B). 2-deep unroll.
template <int USE_BF16, int WRITE_BF16>
__global__ __launch_bounds__(256) void pull_csr_kernel(
    const int* __restrict__ rowptr, const int2* __restrict__ cc,
    const unsigned short* __restrict__ xb_prev,  // bf16 combined prev layer
    const float* __restrict__ xf_prev,           // f32 combined prev layer
    const float4* __restrict__ ue4, const float4* __restrict__ ie4,
    float4* __restrict__ outL4,                  // combined f32 output layer
    ushort4* __restrict__ xb_next)               // bf16 table for next layer
{
    int gid = blockIdx.x * 256 + threadIdx.x;
    int r = gid >> 6;
    if (r >= TROWS) return;
    int lane = threadIdx.x & 63;
    int g = lane >> 4;        // edge slot within wave: 0..3
    int sub = lane & 15;      // 4-float slot within feature row

    float4 acc = make_float4(0.f, 0.f, 0.f, 0.f);
    int end = rowptr[r + 1];
    int e = rowptr[r] + g;

    for (; e + 4 < end; e += 8) {
        int2 m0 = cc[e];
        int2 m1 = cc[e + 4];
        float v0 = __int_as_float(m0.y);
        float v1 = __int_as_float(m1.y);
        float a0, a1, a2, a3, b0, b1, b2, b3;
        if (USE_BF16) {
            uint2 x0 = *(const uint2*)(xb_prev + (size_t)m0.x * DIM + sub * 4);
            uint2 x1 = *(const uint2*)(xb_prev + (size_t)m1.x * DIM + sub * 4);
            a0 = __uint_as_float(x0.x << 16); a1 = __uint_as_float(x0.x & 0xFFFF0000u);
            a2 = __uint_as_float(x0.y << 16); a3 = __uint_as_float(x0.y & 0xFFFF0000u);
            b0 = __uint_as_float(x1.x << 16); b1 = __uint_as_float(x1.x & 0xFFFF0000u);
            b2 = __uint_as_float(x1.y << 16); b3 = __uint_as_float(x1.y & 0xFFFF0000u);
        } else {
            float4 x0 = *(const float4*)(xf_prev + (size_t)m0.x * DIM + sub * 4);
            float4 x1 = *(const float4*)(xf_prev + (size_t)m1.x * DIM + sub * 4);
            a0 = x0.x; a1 = x0.y; a2 = x0.z; a3 = x0.w;
            b0 = x1.x; b1 = x1.y; b2 = x1.z; b3 = x1.w;
        }
        acc.x = fmaf(v0, a0, acc.x);
        acc.y = fmaf(v0, a1, acc.y);
        acc.z = fmaf(v0, a2, acc.z);
        acc.w = fmaf(v0, a3, acc.w);
        acc.x = fmaf(v1, b0, acc.x);
        acc.y = fmaf(v1, b1, acc.y);
        acc.z = fmaf(v1, b2, acc.z);
        acc.w = fmaf(v1, b3, acc.w);
    }
    if (e < end) {
        int2 m0 = cc[e];
        float v0 = __int_as_float(m0.y);
        float a0, a1, a2, a3;
        if (USE_BF16) {
            uint2 x0 = *(const uint2*)(xb_prev + (size_t)m0.x * DIM + sub * 4);
            a0 = __uint_as_float(x0.x << 16); a1 = __uint_as_float(x0.x & 0xFFFF0000u);
            a2 = __uint_as_float(x0.y << 16); a3 = __uint_as_float(x0.y & 0xFFFF0000u);
        } else {
            float4 x0 = *(const float4*)(xf_prev + (size_t)m0.x * DIM + sub * 4);
            a0 = x0.x; a1 = x0.y; a2 = x0.z; a3 = x0.w;
        }
        acc.x = fmaf(v0, a0, acc.x);
        acc.y = fmaf(v0, a1, acc.y);
        acc.z = fmaf(v0, a2, acc.z);
        acc.w = fmaf(v0, a3, acc.w);
    }

    // reduce the 4 edge-groups: lanes {sub, sub+16, sub+32, sub+48}
    acc.x += __shfl_xor(acc.x, 16, 64);
    acc.y += __shfl_xor(acc.y, 16, 64);
    acc.z += __shfl_xor(acc.z, 16, 64);
    acc.w += __shfl_xor(acc.w, 16, 64);
    acc.x += __shfl_xor(acc.x, 32, 64);
    acc.y += __shfl_xor(acc.y, 32, 64);
    acc.z += __shfl_xor(acc.z, 32, 64);
    acc.w += __shfl_xor(acc.w, 32, 64);

    if (g == 0) {
        float4 e0 = (r < NUSERS) ? ue4[(size_t)r * 16 + sub]
                                 : ie4[(size_t)(r - NUSERS) * 16 + sub];
        acc.x = fmaf(ALPHA, e0.x, acc.x);
        acc.y = fmaf(ALPHA, e0.y, acc.y);
        acc.z = fmaf(ALPHA, e0.z, acc.z);
        acc.w = fmaf(ALPHA, e0.w, acc.w);
        outL4[(size_t)r * 16 + sub] = acc;
        if (WRITE_BF16) {
            ushort4 bb;
            bb.x = f2bf(acc.x); bb.y = f2bf(acc.y);
            bb.z = f2bf(acc.z); bb.w = f2bf(acc.w);
            xb_next[(size_t)r * 16 + sub] = bb;
        }
    }
}

// ---------------- fallback (round-1 atomic path) ----------------
__global__ __launch_bounds__(256) void init_out_kernel(const float4* __restrict__ ue,
                                                       const float4* __restrict__ ie,
                                                       float4* __restrict__ out) {
    const int nU4 = NUSERS * DIM / 4;
    const int nT4 = TROWS * DIM / 4;
    int i = blockIdx.x * 256 + threadIdx.x;
    if (i >= nT4) return;
    float4 v = (i < nU4) ? ue[i] : ie[i - nU4];
    out[i] = v;
    float4 a = make_float4(ALPHA * v.x, ALPHA * v.y, ALPHA * v.z, ALPHA * v.w);
    out[nT4 + i] = a;
    out[2 * nT4 + i] = a;
}

__global__ __launch_bounds__(256) void spmm_layer_kernel(
    const int* __restrict__ ui_rows, const int* __restrict__ ui_cols,
    const float* __restrict__ ui_vals,
    const int* __restrict__ iu_rows, const int* __restrict__ iu_cols,
    const float* __restrict__ iu_vals,
    const float* __restrict__ x_items, const float* __restrict__ x_users,
    float* __restrict__ y_users, float* __restrict__ y_items)
{
    unsigned tid = blockIdx.x * 256u + threadIdx.x;
    unsigned d = tid & 63u;
    unsigned e = tid >> 6;
    if (e < NNZ) {
        int r = ui_rows[e];
        int c = ui_cols[e];
        float v = ui_vals[e];
        atomicAdd(&y_users[r * DIM + d], v * x_items[c * DIM + d]);
    } else {
        e -= NNZ;
        if (e < NNZ) {
            int r = iu_rows[e];
            int c = iu_cols[e];
            float v = iu_vals[e];
            atomicAdd(&y_items[r * DIM + d], v * x_users[c * DIM + d]);
        }
    }
}

extern "C" void kernel_launch(void* const* d_in, const int* in_sizes, int n_in,
                              void* d_out, int out_size, void* d_ws, size_t ws_size,
                              hipStream_t stream) {
    const float* ue      = (const float*)d_in[0];
    const float* ie      = (const float*)d_in[1];
    const float* ui_vals = (const float*)d_in[2];
    const float* iu_vals = (const float*)d_in[3];
    const int*   ui_rows = (const int*)d_in[4];
    const int*   ui_cols = (const int*)d_in[5];
    const int*   iu_rows = (const int*)d_in[6];
    const int*   iu_cols = (const int*)d_in[7];
    float* out = (float*)d_out;

    float* L1 = out + (size_t)LSTRIDE;
    float* L2 = out + (size_t)2 * LSTRIDE;

    // ws layout: gcounts[1280] gbase[1280] gcursor[1280] rowptr[150032]
    //            | binned int2[NEDGES] | binned2 int2[NEDGES]
    //            | xb0 ushort[TROWS*64] | xb1 ushort[TROWS*64]
    const size_t NB_PAD = 1280;
    const size_t RP_PAD = 150032;
    const size_t hdr_bytes    = (NB_PAD * 3 + RP_PAD) * 4;   // 615488, 16B-aligned
    const size_t binned_bytes = (size_t)NEDGES * 8;          // 25.6 MB
    const size_t xb_bytes     = (size_t)TROWS * DIM * 2;     // 19.2 MB
    const size_t need_f32  = hdr_bytes + 2 * binned_bytes;             // ~51.8 MB
    const size_t need_bf16 = need_f32 + 2 * xb_bytes;                  // ~90.2 MB

    if (ws_size < need_f32) {
        // last-resort fallback: atomic scatter path (round-1, known-good)
        const int nT4 = TROWS * DIM / 4;
        init_out_kernel<<<(nT4 + 255) / 256, 256, 0, stream>>>(
            (const float4*)ue, (const float4*)ie, (float4*)out);
        float* u1 = L1; float* i1 = L1 + (size_t)NUSERS * DIM;
        float* u2 = L2; float* i2 = L2 + (size_t)NUSERS * DIM;
        const unsigned nblocks = (2u * NNZ * 64u) / 256u;
        spmm_layer_kernel<<<nblocks, 256, 0, stream>>>(
            ui_rows, ui_cols, ui_vals, iu_rows, iu_cols, iu_vals, ie, ue, u1, i1);
        spmm_layer_kernel<<<nblocks, 256, 0, stream>>>(
            ui_rows, ui_cols, ui_vals, iu_rows, iu_cols, iu_vals, i1, u1, u2, i2);
        return;
    }

    int* gcounts = (int*)d_ws;
    int* gbase   = gcounts + NB_PAD;
    int* gcursor = gbase + NB_PAD;
    int* rowptr  = gcursor + NB_PAD;
    int2* binned  = (int2*)((char*)d_ws + hdr_bytes);
    int2* binned2 = (int2*)((char*)binned + binned_bytes);
    unsigned short* xb0 = (unsigned short*)((char*)binned2 + binned_bytes);
    unsigned short* xb1 = xb0 + (size_t)TROWS * DIM;

    const bool use_bf16 = (ws_size >= need_bf16);

    hipMemsetAsync(gcounts, 0, NB_PAD * sizeof(int), stream);

    const int nT4 = TROWS * DIM / 4;
    if (use_bf16)
        init_copy_kernel<1><<<(nT4 + 255) / 256, 256, 0, stream>>>(
            (const float4*)ue, (const float4*)ie, (float4*)out, (ushort4*)xb0);
    else
        init_copy_kernel<0><<<(nT4 + 255) / 256, 256, 0, stream>>>(
            (const float4*)ue, (const float4*)ie, (float4*)out, nullptr);

    bucket_hist_kernel<<<NBCHUNK, 256, 0, stream>>>(ui_rows, iu_rows, gcounts);
    scan_buckets_kernel<<<1, 64, 0, stream>>>(gcounts, gbase, gcursor, rowptr);
    bin_scatter_kernel<<<NBCHUNK, 256, 0, stream>>>(
        ui_rows, ui_cols, ui_vals, iu_rows, iu_cols, iu_vals, gcursor, binned);
    csr_sort_kernel<<<NBUCK, 256, 0, stream>>>(gbase, gcounts, binned, binned2, rowptr);

    const float4* ue4 = (const float4*)ue;
    const float4* ie4 = (const float4*)ie;
    const int pgrid = (TROWS * DIM) / 256;   // 37500 blocks
    if (use_bf16) {
        pull_csr_kernel<1, 1><<<pgrid, 256, 0, stream>>>(
            rowptr, binned2, xb0, nullptr, ue4, ie4, (float4*)L1, (ushort4*)xb1);
        pull_csr_kernel<1, 0><<<pgrid, 256, 0, stream>>>(
            rowptr, binned2, xb1, nullptr, ue4, ie4, (float4*)L2, nullptr);
    } else {
        pull_csr_kernel<0, 0><<<pgrid, 256, 0, stream>>>(
            rowptr, binned2, nullptr, out, ue4, ie4, (float4*)L1, nullptr);
        pull_csr_kernel<0, 0><<<pgrid, 256, 0, stream>>>(
            rowptr, binned2, nullptr, L1, ue4, ie4, (float4*)L2, nullptr);
    }
}

// Round 6
// 333.886 us; speedup vs baseline: 7.5039x; 1.1054x over previous
//
#include <hip/hip_runtime.h>

#define NUSERS 100000
#define NITEMS 50000
#define DIM 64
#define NNZ 1600000
#define ALPHA 0.1f
#define TROWS (NUSERS + NITEMS)   // 150000 combined rows
#define LSTRIDE (TROWS * DIM)
#define NEDGES (2 * NNZ)          // 3.2M combined edges

#define BROWS 128                           // rows per bucket
#define NBUCK ((TROWS + BROWS - 1) / BROWS) // 1172

#define CH_H 4096                               // edges per hist block
#define NCHUNK_H ((NEDGES + CH_H - 1) / CH_H)   // 782
#define CH_S 8192                               // edges per scatter block
#define NCHUNK_S ((NEDGES + CH_S - 1) / CH_S)   // 391

__device__ __forceinline__ unsigned short f2bf(float f) {
    unsigned u = __float_as_uint(f);
    unsigned r = (u + 0x7FFFu + ((u >> 16) & 1u)) >> 16;   // RNE
    return (unsigned short)r;
}

// ---------------- layer-0 copy (+ optional bf16 table) ----------------
template <int MAKE_BF16>
__global__ __launch_bounds__(256) void init_copy_kernel(const float4* __restrict__ ue,
                                                        const float4* __restrict__ ie,
                                                        float4* __restrict__ out,
                                                        ushort4* __restrict__ xb0) {
    const int nU4 = NUSERS * DIM / 4;
    const int nT4 = TROWS * DIM / 4;
    int i = blockIdx.x * 256 + threadIdx.x;
    if (i >= nT4) return;
    float4 v = (i < nU4) ? ue[i] : ie[i - nU4];
    out[i] = v;
    if (MAKE_BF16) {
        ushort4 b;
        b.x = f2bf(v.x); b.y = f2bf(v.y); b.z = f2bf(v.z); b.w = f2bf(v.w);
        xb0[i] = b;
    }
}

// ---------------- bucket histogram (block-privatized, int LDS atomics) ----------------
__global__ __launch_bounds__(256) void bucket_hist_kernel(const int* __restrict__ ui_rows,
                                                          const int* __restrict__ iu_rows,
                                                          int* __restrict__ gcounts) {
    __shared__ int h[NBUCK];
    for (int t = threadIdx.x; t < NBUCK; t += 256) h[t] = 0;
    __syncthreads();
    int base = blockIdx.x * CH_H;
    for (int j = threadIdx.x; j < CH_H; j += 256) {
        int i = base + j;
        if (i >= NEDGES) break;
        int crow = (i < NNZ) ? ui_rows[i] : (NUSERS + iu_rows[i - NNZ]);
        atomicAdd(&h[crow >> 7], 1);
    }
    __syncthreads();
    for (int t = threadIdx.x; t < NBUCK; t += 256) {
        int c = h[t];
        if (c) atomicAdd(&gcounts[t], c);
    }
}

// ---------------- exclusive scan of bucket counts (one wave) ----------------
__global__ void scan_buckets_kernel(const int* __restrict__ gcounts,
                                    int* __restrict__ gbase,
                                    int* __restrict__ gcursor,
                                    int* __restrict__ rowptr) {
    int lane = threadIdx.x;   // blockDim = 64, single wave
    int carry = 0;
    for (int b0 = 0; b0 < NBUCK; b0 += 64) {
        int idx = b0 + lane;
        int c = (idx < NBUCK) ? gcounts[idx] : 0;
        int x = c;
        for (int off = 1; off < 64; off <<= 1) {
            int u = __shfl_up(x, off, 64);
            if (lane >= off) x += u;
        }
        int excl = carry + x - c;
        if (idx < NBUCK) { gbase[idx] = excl; gcursor[idx] = excl; }
        carry += __shfl(x, 63, 64);
    }
    if (lane == 0) rowptr[TROWS] = NEDGES;   // sentinel
}

// ---------------- binned scatter: contiguous per-(block,bucket) runs ----------------
// payload word0 = src | (row_local << 18)   (src < 2^18, row_local < 128)
__global__ __launch_bounds__(512) void bin_scatter_kernel(
    const int* __restrict__ ui_rows, const int* __restrict__ ui_cols,
    const float* __restrict__ ui_vals,
    const int* __restrict__ iu_rows, const int* __restrict__ iu_cols,
    const float* __restrict__ iu_vals,
    int* __restrict__ gcursor, int2* __restrict__ binned)
{
    __shared__ int h[NBUCK];
    __shared__ int bbase[NBUCK];
    for (int t = threadIdx.x; t < NBUCK; t += 512) h[t] = 0;
    __syncthreads();
    int base = blockIdx.x * CH_S;
    for (int j = threadIdx.x; j < CH_S; j += 512) {
        int i = base + j;
        if (i >= NEDGES) break;
        int crow = (i < NNZ) ? ui_rows[i] : (NUSERS + iu_rows[i - NNZ]);
        atomicAdd(&h[crow >> 7], 1);
    }
    __syncthreads();
    for (int t = threadIdx.x; t < NBUCK; t += 512) {
        int c = h[t];
        bbase[t] = c ? atomicAdd(&gcursor[t], c) : 0;
        h[t] = 0;
    }
    __syncthreads();
    for (int j = threadIdx.x; j < CH_S; j += 512) {
        int i = base + j;
        if (i >= NEDGES) break;
        int crow, src; float val;
        if (i < NNZ) {
            crow = ui_rows[i]; src = NUSERS + ui_cols[i]; val = ui_vals[i];
        } else {
            int k = i - NNZ;
            crow = NUSERS + iu_rows[k]; src = iu_cols[k]; val = iu_vals[k];
        }
        int b = crow >> 7;
        int off = atomicAdd(&h[b], 1);
        binned[bbase[b] + off] = make_int2(src | ((crow & 127) << 18), __float_as_int(val));
    }
}

// ---------------- bucket-local CSR sort: binned -> binned2 (row-sorted) ----------------
// One block per bucket. Reads/writes stay inside the bucket's ~22KB window
// (same XCD, L2-merged). Also emits the global rowptr.
__global__ __launch_bounds__(512) void csr_sort_kernel(
    const int* __restrict__ gbase, const int* __restrict__ gcounts,
    const int2* __restrict__ binned, int2* __restrict__ binned2,
    int* __restrict__ rowptr)
{
    __shared__ int h[BROWS];
    __shared__ int off[BROWS];
    __shared__ int cur[BROWS];
    int b = blockIdx.x;
    int s = gbase[b];
    int n = gcounts[b];
    int t = threadIdx.x;
    if (t < BROWS) h[t] = 0;
    __syncthreads();
    for (int j = t; j < n; j += 512)
        atomicAdd(&h[((unsigned)binned[s + j].x) >> 18], 1);
    __syncthreads();
    if (t < BROWS) off[t] = h[t];
    __syncthreads();
    for (int d = 1; d < BROWS; d <<= 1) {
        int v = 0;
        if (t < BROWS && t >= d) v = off[t - d];
        __syncthreads();
        if (t < BROWS) off[t] += v;
        __syncthreads();
    }
    if (t < BROWS) {
        int excl = off[t] - h[t];     // exclusive scan
        cur[t] = excl;
        int row = b * BROWS + t;
        if (row < TROWS) rowptr[row] = s + excl;
    }
    __syncthreads();
    for (int j = t; j < n; j += 512) {
        int2 m = binned[s + j];
        unsigned w = (unsigned)m.x;
        int pos = atomicAdd(&cur[w >> 18], 1);
        binned2[s + pos] = make_int2((int)(w & 0x3FFFFu), m.y);
    }
}

// ---------------- CSR pull: one wave per output row, register accumulate ----------------
// Wave = 4 edge-groups x 16 lanes; group covers the full feature row of its
// edge (bf16: uint2/lane = 128B; f32: float4/lane = 256B). 2-deep unroll.
template <int USE_BF16, int WRITE_BF16>
__global__ __launch_bounds__(256) void pull_csr_kernel(
    const int* __restrict__ rowptr, const int2* __restrict__ cc,
    const unsigned short* __restrict__ xb_prev,  // bf16 combined prev layer
    const float* __restrict__ xf_prev,           // f32 combined prev layer
    const float4* __restrict__ ue4, const float4* __restrict__ ie4,
    float4* __restrict__ outL4,                  // combined f32 output layer
    ushort4* __restrict__ xb_next)               // bf16 table for next layer
{
    int gid = blockIdx.x * 256 + threadIdx.x;
    int r = gid >> 6;
    if (r >= TROWS) return;
    int lane = threadIdx.x & 63;
    int g = lane >> 4;        // edge slot within wave: 0..3
    int sub = lane & 15;      // 4-float slot within feature row

    float4 acc = make_float4(0.f, 0.f, 0.f, 0.f);
    int end = rowptr[r + 1];
    int e = rowptr[r] + g;

    for (; e + 4 < end; e += 8) {
        int2 m0 = cc[e];
        int2 m1 = cc[e + 4];
        float v0 = __int_as_float(m0.y);
        float v1 = __int_as_float(m1.y);
        float a0, a1, a2, a3, b0, b1, b2, b3;
        if (USE_BF16) {
            uint2 x0 = *(const uint2*)(xb_prev + (size_t)m0.x * DIM + sub * 4);
            uint2 x1 = *(const uint2*)(xb_prev + (size_t)m1.x * DIM + sub * 4);
            a0 = __uint_as_float(x0.x << 16); a1 = __uint_as_float(x0.x & 0xFFFF0000u);
            a2 = __uint_as_float(x0.y << 16); a3 = __uint_as_float(x0.y & 0xFFFF0000u);
            b0 = __uint_as_float(x1.x << 16); b1 = __uint_as_float(x1.x & 0xFFFF0000u);
            b2 = __uint_as_float(x1.y << 16); b3 = __uint_as_float(x1.y & 0xFFFF0000u);
        } else {
            float4 x0 = *(const float4*)(xf_prev + (size_t)m0.x * DIM + sub * 4);
            float4 x1 = *(const float4*)(xf_prev + (size_t)m1.x * DIM + sub * 4);
            a0 = x0.x; a1 = x0.y; a2 = x0.z; a3 = x0.w;
            b0 = x1.x; b1 = x1.y; b2 = x1.z; b3 = x1.w;
        }
        acc.x = fmaf(v0, a0, acc.x);
        acc.y = fmaf(v0, a1, acc.y);
        acc.z = fmaf(v0, a2, acc.z);
        acc.w = fmaf(v0, a3, acc.w);
        acc.x = fmaf(v1, b0, acc.x);
        acc.y = fmaf(v1, b1, acc.y);
        acc.z = fmaf(v1, b2, acc.z);
        acc.w = fmaf(v1, b3, acc.w);
    }
    if (e < end) {
        int2 m0 = cc[e];
        float v0 = __int_as_float(m0.y);
        float a0, a1, a2, a3;
        if (USE_BF16) {
            uint2 x0 = *(const uint2*)(xb_prev + (size_t)m0.x * DIM + sub * 4);
            a0 = __uint_as_float(x0.x << 16); a1 = __uint_as_float(x0.x & 0xFFFF0000u);
            a2 = __uint_as_float(x0.y << 16); a3 = __uint_as_float(x0.y & 0xFFFF0000u);
        } else {
            float4 x0 = *(const float4*)(xf_prev + (size_t)m0.x * DIM + sub * 4);
            a0 = x0.x; a1 = x0.y; a2 = x0.z; a3 = x0.w;
        }
        acc.x = fmaf(v0, a0, acc.x);
        acc.y = fmaf(v0, a1, acc.y);
        acc.z = fmaf(v0, a2, acc.z);
        acc.w = fmaf(v0, a3, acc.w);
    }

    // reduce the 4 edge-groups: lanes {sub, sub+16, sub+32, sub+48}
    acc.x += __shfl_xor(acc.x, 16, 64);
    acc.y += __shfl_xor(acc.y, 16, 64);
    acc.z += __shfl_xor(acc.z, 16, 64);
    acc.w += __shfl_xor(acc.w, 16, 64);
    acc.x += __shfl_xor(acc.x, 32, 64);
    acc.y += __shfl_xor(acc.y, 32, 64);
    acc.z += __shfl_xor(acc.z, 32, 64);
    acc.w += __shfl_xor(acc.w, 32, 64);

    if (g == 0) {
        float4 e0 = (r < NUSERS) ? ue4[(size_t)r * 16 + sub]
                                 : ie4[(size_t)(r - NUSERS) * 16 + sub];
        acc.x = fmaf(ALPHA, e0.x, acc.x);
        acc.y = fmaf(ALPHA, e0.y, acc.y);
        acc.z = fmaf(ALPHA, e0.z, acc.z);
        acc.w = fmaf(ALPHA, e0.w, acc.w);
        outL4[(size_t)r * 16 + sub] = acc;
        if (WRITE_BF16) {
            ushort4 bb;
            bb.x = f2bf(acc.x); bb.y = f2bf(acc.y);
            bb.z = f2bf(acc.z); bb.w = f2bf(acc.w);
            xb_next[(size_t)r * 16 + sub] = bb;
        }
    }
}

// ---------------- fallback (round-1 atomic path) ----------------
__global__ __launch_bounds__(256) void init_out_kernel(const float4* __restrict__ ue,
                                                       const float4* __restrict__ ie,
                                                       float4* __restrict__ out) {
    const int nU4 = NUSERS * DIM / 4;
    const int nT4 = TROWS * DIM / 4;
    int i = blockIdx.x * 256 + threadIdx.x;
    if (i >= nT4) return;
    float4 v = (i < nU4) ? ue[i] : ie[i - nU4];
    out[i] = v;
    float4 a = make_float4(ALPHA * v.x, ALPHA * v.y, ALPHA * v.z, ALPHA * v.w);
    out[nT4 + i] = a;
    out[2 * nT4 + i] = a;
}

__global__ __launch_bounds__(256) void spmm_layer_kernel(
    const int* __restrict__ ui_rows, const int* __restrict__ ui_cols,
    const float* __restrict__ ui_vals,
    const int* __restrict__ iu_rows, const int* __restrict__ iu_cols,
    const float* __restrict__ iu_vals,
    const float* __restrict__ x_items, const float* __restrict__ x_users,
    float* __restrict__ y_users, float* __restrict__ y_items)
{
    unsigned tid = blockIdx.x * 256u + threadIdx.x;
    unsigned d = tid & 63u;
    unsigned e = tid >> 6;
    if (e < NNZ) {
        int r = ui_rows[e];
        int c = ui_cols[e];
        float v = ui_vals[e];
        atomicAdd(&y_users[r * DIM + d], v * x_items[c * DIM + d]);
    } else {
        e -= NNZ;
        if (e < NNZ) {
            int r = iu_rows[e];
            int c = iu_cols[e];
            float v = iu_vals[e];
            atomicAdd(&y_items[r * DIM + d], v * x_users[c * DIM + d]);
        }
    }
}

extern "C" void kernel_launch(void* const* d_in, const int* in_sizes, int n_in,
                              void* d_out, int out_size, void* d_ws, size_t ws_size,
                              hipStream_t stream) {
    const float* ue      = (const float*)d_in[0];
    const float* ie      = (const float*)d_in[1];
    const float* ui_vals = (const float*)d_in[2];
    const float* iu_vals = (const float*)d_in[3];
    const int*   ui_rows = (const int*)d_in[4];
    const int*   ui_cols = (const int*)d_in[5];
    const int*   iu_rows = (const int*)d_in[6];
    const int*   iu_cols = (const int*)d_in[7];
    float* out = (float*)d_out;

    float* L1 = out + (size_t)LSTRIDE;
    float* L2 = out + (size_t)2 * LSTRIDE;

    // ws layout: gcounts[1280] gbase[1280] gcursor[1280] rowptr[150032]
    //            | binned int2[NEDGES] | binned2 int2[NEDGES]
    //            | xb0 ushort[TROWS*64] | xb1 ushort[TROWS*64]
    const size_t NB_PAD = 1280;
    const size_t RP_PAD = 150032;
    const size_t hdr_bytes    = (NB_PAD * 3 + RP_PAD) * 4;   // 615488, 16B-aligned
    const size_t binned_bytes = (size_t)NEDGES * 8;          // 25.6 MB
    const size_t xb_bytes     = (size_t)TROWS * DIM * 2;     // 19.2 MB
    const size_t need_f32  = hdr_bytes + 2 * binned_bytes;             // ~51.8 MB
    const size_t need_bf16 = need_f32 + 2 * xb_bytes;                  // ~90.2 MB

    if (ws_size < need_f32) {
        // last-resort fallback: atomic scatter path (round-1, known-good)
        const int nT4 = TROWS * DIM / 4;
        init_out_kernel<<<(nT4 + 255) / 256, 256, 0, stream>>>(
            (const float4*)ue, (const float4*)ie, (float4*)out);
        float* u1 = L1; float* i1 = L1 + (size_t)NUSERS * DIM;
        float* u2 = L2; float* i2 = L2 + (size_t)NUSERS * DIM;
        const unsigned nblocks = (2u * NNZ * 64u) / 256u;
        spmm_layer_kernel<<<nblocks, 256, 0, stream>>>(
            ui_rows, ui_cols, ui_vals, iu_rows, iu_cols, iu_vals, ie, ue, u1, i1);
        spmm_layer_kernel<<<nblocks, 256, 0, stream>>>(
            ui_rows, ui_cols, ui_vals, iu_rows, iu_cols, iu_vals, i1, u1, u2, i2);
        return;
    }

    int* gcounts = (int*)d_ws;
    int* gbase   = gcounts + NB_PAD;
    int* gcursor = gbase + NB_PAD;
    int* rowptr  = gcursor + NB_PAD;
    int2* binned  = (int2*)((char*)d_ws + hdr_bytes);
    int2* binned2 = (int2*)((char*)binned + binned_bytes);
    unsigned short* xb0 = (unsigned short*)((char*)binned2 + binned_bytes);
    unsigned short* xb1 = xb0 + (size_t)TROWS * DIM;

    const bool use_bf16 = (ws_size >= need_bf16);

    hipMemsetAsync(gcounts, 0, NB_PAD * sizeof(int), stream);

    const int nT4 = TROWS * DIM / 4;
    if (use_bf16)
        init_copy_kernel<1><<<(nT4 + 255) / 256, 256, 0, stream>>>(
            (const float4*)ue, (const float4*)ie, (float4*)out, (ushort4*)xb0);
    else
        init_copy_kernel<0><<<(nT4 + 255) / 256, 256, 0, stream>>>(
            (const float4*)ue, (const float4*)ie, (float4*)out, nullptr);

    bucket_hist_kernel<<<NCHUNK_H, 256, 0, stream>>>(ui_rows, iu_rows, gcounts);
    scan_buckets_kernel<<<1, 64, 0, stream>>>(gcounts, gbase, gcursor, rowptr);
    bin_scatter_kernel<<<NCHUNK_S, 512, 0, stream>>>(
        ui_rows, ui_cols, ui_vals, iu_rows, iu_cols, iu_vals, gcursor, binned);
    csr_sort_kernel<<<NBUCK, 512, 0, stream>>>(gbase, gcounts, binned, binned2, rowptr);

    const float4* ue4 = (const float4*)ue;
    const float4* ie4 = (const float4*)ie;
    const int pgrid = (TROWS * DIM) / 256;   // 37500 blocks
    if (use_bf16) {
        pull_csr_kernel<1, 1><<<pgrid, 256, 0, stream>>>(
            rowptr, binned2, xb0, nullptr, ue4, ie4, (float4*)L1, (ushort4*)xb1);
        pull_csr_kernel<1, 0><<<pgrid, 256, 0, stream>>>(
            rowptr, binned2, xb1, nullptr, ue4, ie4, (float4*)L2, nullptr);
    } else {
        pull_csr_kernel<0, 0><<<pgrid, 256, 0, stream>>>(
            rowptr, binned2, nullptr, out, ue4, ie4, (float4*)L1, nullptr);
        pull_csr_kernel<0, 0><<<pgrid, 256, 0, stream>>>(
            rowptr, binned2, nullptr, L1, ue4, ie4, (float4*)L2, nullptr);
    }
}